// Round 3
// baseline (618.064 us; speedup 1.0000x reference)
//
#include <hip/hip_runtime.h>

// ============================================================================
// Qudit gate apply: state (4,)^12 complex (f32 re/im planes), gate 1024x1024
// complex on target axes (0,3,5,8,11).
// GEMM: C[b][n] = sum_k A[b][k] * Bt[n][k]
//   A[b][k]  : k<1024 -> qs_re gathered at (b, c=k); k>=1024 -> qs_im
//   Bt[n][k] : complex-as-real blocks [[Gr, -Gi],[Gi, Gr]] (transposed layout)
//   C[b][n]  : n<1024 -> out_re at (b, r=n); else out_im
// Precision: split-bf16 (x = hi + lo), 3 MFMA terms hh+hl+lh -> ~2^-17 rel err.
// R2 change: A is gathered f32 + split + LDS-written IN the GEMM (no
// pack_state kernel) — packed A had the same byte count as raw state, so the
// pack was a pure 384 MB round trip (~210 us). B stays packed (pack_gate,
// ~16 us) and staged via global_load_lds(16B) with pre-swizzled source.
// ============================================================================

typedef unsigned short u16;
typedef unsigned int u32;
typedef __bf16 bf16x8 __attribute__((ext_vector_type(8)));
typedef float f32x4 __attribute__((ext_vector_type(4)));

// ---- digit scatter helpers -------------------------------------------------
// batch digits (LSB first) -> axes 10,9,7,6,4,2,1 with float strides
// 4,16,256,1024,16384,262144,1048576
__device__ __forceinline__ int scat_b(int b) {
    return ((b & 3) << 2) + (((b >> 2) & 3) << 4) + (((b >> 4) & 3) << 8) +
           (((b >> 6) & 3) << 10) + (((b >> 8) & 3) << 14) +
           (((b >> 10) & 3) << 18) + (((b >> 12) & 3) << 20);
}

// f32 -> bf16 hi (RNE) + bf16 lo (residual, RNE)
__device__ __forceinline__ void bsplit(float x, u16& h, u16& l) {
    u32 b  = __float_as_uint(x);
    u32 hb = (b + 0x7FFFu + ((b >> 16) & 1u)) & 0xFFFF0000u;
    h = (u16)(hb >> 16);
    float r = x - __uint_as_float(hb);
    u32 rb = __float_as_uint(r);
    l = (u16)((rb + 0x7FFFu + ((rb >> 16) & 1u)) >> 16);
}

__device__ __forceinline__ f32x4 mfma16(bf16x8 a, bf16x8 b, f32x4 c) {
    return __builtin_amdgcn_mfma_f32_16x16x32_bf16(a, b, c, 0, 0, 0);
}

__device__ __forceinline__ void gll16(const void* g, void* l) {
    __builtin_amdgcn_global_load_lds(
        (const __attribute__((address_space(1))) u32*)g,
        (__attribute__((address_space(3))) u32*)l, 16, 0, 0);
}

// ============================================================================
// pack_gate: Bt[n][k] bf16 hi/lo, n-major rows of 2048.  grid 2048 x 256
// ============================================================================
__global__ void pack_gate(const float* __restrict__ gre,
                          const float* __restrict__ gim,
                          u16* __restrict__ bh, u16* __restrict__ bl) {
    int t = blockIdx.x * 256 + threadIdx.x;  // 524288 threads
    int n = t >> 8;                          // 0..2047
    int k = (t & 255) << 3;                  // 8-elem segment
    bool nim = n >= 1024, kim = k >= 1024;
    const float* src = kim ? (nim ? gre : gim) : (nim ? gim : gre);
    float sgn = (kim && !nim) ? -1.f : 1.f;
    int r = n & 1023, c = k & 1023;
    const float* p = src + r * 1024 + c;
    float4 v0 = *(const float4*)p;
    float4 v1 = *(const float4*)(p + 4);
    u16 h[8], l[8];
    bsplit(v0.x * sgn, h[0], l[0]); bsplit(v0.y * sgn, h[1], l[1]);
    bsplit(v0.z * sgn, h[2], l[2]); bsplit(v0.w * sgn, h[3], l[3]);
    bsplit(v1.x * sgn, h[4], l[4]); bsplit(v1.y * sgn, h[5], l[5]);
    bsplit(v1.z * sgn, h[6], l[6]); bsplit(v1.w * sgn, h[7], l[7]);
    size_t o = (size_t)n * 2048 + k;
    uint4 hw, lw;
    hw.x = h[0] | ((u32)h[1] << 16); hw.y = h[2] | ((u32)h[3] << 16);
    hw.z = h[4] | ((u32)h[5] << 16); hw.w = h[6] | ((u32)h[7] << 16);
    lw.x = l[0] | ((u32)l[1] << 16); lw.y = l[2] | ((u32)l[3] << 16);
    lw.z = l[4] | ((u32)l[5] << 16); lw.w = l[6] | ((u32)l[7] << 16);
    *(uint4*)(bh + o) = hw;
    *(uint4*)(bl + o) = lw;
}

// ============================================================================
// GEMM:  BM=BN=128, BK=64, 256 thr (4 waves 2x2, wave tile 64x64 = 4x4 frags
// of 16x16x32).  LDS tiles XOR-swizzled: byte ^= (row&7)<<4 (2-way = free).
// A: gathered f32 from state, bsplit, swizzled ds_write (reg-staged).
// BPACK: B staged via global_load_lds from packed ws; else gathered f32.
// ============================================================================
__device__ __forceinline__ void stage_packed(const u16* gh, const u16* gl,
                                             int row0, int kt, u16* sh,
                                             u16* sl, int wid, int lane) {
#pragma unroll
    for (int i = 0; i < 4; ++i) {
        int chunk = (wid << 2) + i;         // 16 chunks of 8 rows
        int rl = (chunk << 3) + (lane >> 3);
        size_t off = (size_t)(row0 + rl) * 2048 + kt +
                     (((lane & 7) ^ (rl & 7)) << 3);  // pre-swizzled source
        gll16(gh + off, sh + chunk * 512);  // dest wave-uniform, linear
        gll16(gl + off, sl + chunk * 512);
    }
}

__device__ __forceinline__ void cvtwrite(const float4 v[8], int row, int half,
                                         char* sh, char* sl) {
    int swz = (row & 7) << 4;
#pragma unroll
    for (int q = 0; q < 8; ++q) {
        u16 h0, h1, h2, h3, l0, l1, l2, l3;
        bsplit(v[q].x, h0, l0); bsplit(v[q].y, h1, l1);
        bsplit(v[q].z, h2, l2); bsplit(v[q].w, h3, l3);
        int off = row * 128 + (((half << 6) + (q << 3)) ^ swz);
        uint2 hw, lw;
        hw.x = h0 | ((u32)h1 << 16); hw.y = h2 | ((u32)h3 << 16);
        lw.x = l0 | ((u32)l1 << 16); lw.y = l2 | ((u32)l3 << 16);
        *(uint2*)(sh + off) = hw;
        *(uint2*)(sl + off) = lw;
    }
}

// A gather: 8 c-quads for (row, half) of tile at kt
// v[q] = state floats at c4=0..3, c3=q&3, c2=2*half+(q>>2), c1/c0 from kt
__device__ __forceinline__ void loadA(const float* qre, const float* qim,
                                      int bb, int half, int kt, float4 v[8]) {
    const float* src = (kt < 1024) ? qre : qim;
    int km = kt & 1023;
    int cof = (((km >> 6) & 3) << 16) + (((km >> 8) & 3) << 22);
    const float* p = src + bb + cof + (half << 13);
    v[0] = *(const float4*)(p);
    v[1] = *(const float4*)(p + 64);
    v[2] = *(const float4*)(p + 128);
    v[3] = *(const float4*)(p + 192);
    v[4] = *(const float4*)(p + 4096);
    v[5] = *(const float4*)(p + 4160);
    v[6] = *(const float4*)(p + 4224);
    v[7] = *(const float4*)(p + 4288);
}

// B gather from gate f32 (no-ws fallback); sign folded via sgn
__device__ __forceinline__ void loadB(const float* gre, const float* gim,
                                      int n0, int kt, int row, int half,
                                      float4 v[8], float& sgn) {
    bool nim = n0 >= 1024, kim = kt >= 1024;
    const float* src = kim ? (nim ? gre : gim) : (nim ? gim : gre);
    sgn = (kim && !nim) ? -1.f : 1.f;
    int r = (n0 + row) & 1023;
    const float* p = src + r * 1024 + (kt & 1023) + (half << 5);
#pragma unroll
    for (int q = 0; q < 8; ++q) v[q] = *(const float4*)(p + q * 4);
}

template <bool BPACK>
__global__ __launch_bounds__(256, 2) void gemm_k(
    const float* __restrict__ qre, const float* __restrict__ qim,
    const float* __restrict__ gre, const float* __restrict__ gim,
    const u16* __restrict__ Bh, const u16* __restrict__ Bl,
    float* __restrict__ out) {
    __shared__ __align__(16) u16 sAh[128 * 64];
    __shared__ __align__(16) u16 sAl[128 * 64];
    __shared__ __align__(16) u16 sBh[128 * 64];
    __shared__ __align__(16) u16 sBl[128 * 64];

    int tid = threadIdx.x;
    int lane = tid & 63, wid = tid >> 6;

    // XCD-aware bijective swizzle (2048 % 8 == 0), nt-major decomposition:
    // XCD x owns orig in [x*256, (x+1)*256) = 2 nt-panels x 128 mt
    // -> 2 MB of packed B stays L2-resident per XCD; A streams via L3.
    int bid = blockIdx.x;
    int orig = ((bid & 7) << 8) + (bid >> 3);
    int nt = orig >> 7, mt = orig & 127;
    int m0 = mt << 7, n0 = nt << 7;

    // staging role
    int srow = tid >> 1, shalf = tid & 1;
    int bb = scat_b(m0 + srow);

    float4 av[8], bv[8];
    float bsgn = 1.f;
    loadA(qre, qim, bb, shalf, 0, av);
    if constexpr (!BPACK) loadB(gre, gim, n0, 0, srow, shalf, bv, bsgn);
    if constexpr (BPACK) stage_packed(Bh, Bl, n0, 0, sBh, sBl, wid, lane);

    // compute role
    int wm = wid >> 1, wn = wid & 1;
    int aoffs[4], boffs[4];
#pragma unroll
    for (int f = 0; f < 4; ++f) {
        aoffs[f] = (wm * 64 + f * 16 + (lane & 15)) * 128;
        boffs[f] = (wn * 64 + f * 16 + (lane & 15)) * 128;
    }
    int swz = (lane & 7) << 4;
    int koff0 = (((lane >> 4) << 4)) ^ swz;
    int koff1 = (64 + ((lane >> 4) << 4)) ^ swz;

    f32x4 acc[4][4];
#pragma unroll
    for (int i = 0; i < 4; ++i)
#pragma unroll
        for (int j = 0; j < 4; ++j) acc[i][j] = (f32x4){0.f, 0.f, 0.f, 0.f};

    for (int it = 0; it < 32; ++it) {
        int kt = it << 6;
        cvtwrite(av, srow, shalf, (char*)sAh, (char*)sAl);
        if constexpr (!BPACK) {
            float4 bs[8];
#pragma unroll
            for (int q = 0; q < 8; ++q) {
                bs[q].x = bv[q].x * bsgn; bs[q].y = bv[q].y * bsgn;
                bs[q].z = bv[q].z * bsgn; bs[q].w = bv[q].w * bsgn;
            }
            cvtwrite(bs, srow, shalf, (char*)sBh, (char*)sBl);
        }
        __syncthreads();  // LDS writes + global_load_lds(kt) complete
        if (it < 31) {    // prefetch next gathered tiles into regs
            loadA(qre, qim, bb, shalf, kt + 64, av);
            if constexpr (!BPACK)
                loadB(gre, gim, n0, kt + 64, srow, shalf, bv, bsgn);
        }
#pragma unroll
        for (int ks = 0; ks < 2; ++ks) {
            int ko = ks ? koff1 : koff0;
            bf16x8 a_h[4], a_l[4], b_h[4], b_l[4];
#pragma unroll
            for (int f = 0; f < 4; ++f) {
                a_h[f] = *(const bf16x8*)((const char*)sAh + aoffs[f] + ko);
                a_l[f] = *(const bf16x8*)((const char*)sAl + aoffs[f] + ko);
                b_h[f] = *(const bf16x8*)((const char*)sBh + boffs[f] + ko);
                b_l[f] = *(const bf16x8*)((const char*)sBl + boffs[f] + ko);
            }
#pragma unroll
            for (int i = 0; i < 4; ++i)
#pragma unroll
                for (int j = 0; j < 4; ++j) {
                    acc[i][j] = mfma16(a_h[i], b_h[j], acc[i][j]);
                    acc[i][j] = mfma16(a_l[i], b_h[j], acc[i][j]);
                    acc[i][j] = mfma16(a_h[i], b_l[j], acc[i][j]);
                }
        }
        __syncthreads();  // frag reads done before next overwrite
        if (it < 31) {
            if constexpr (BPACK)
                stage_packed(Bh, Bl, n0, kt + 64, sBh, sBl, wid, lane);
        }
    }

    // epilogue: scatter f32 directly into state layout
    int mbase = scat_b(m0 + wm * 64);
    int nw = n0 + wn * 64;
    float* op = out + ((nw >> 10) << 24);  // re plane or im plane (+16M)
    int rb = nw & 1023;
    int rbase = (((rb >> 2) & 3) << 6) + (((rb >> 4) & 3) << 12) +
                (((rb >> 6) & 3) << 16) + (((rb >> 8) & 3) << 22);
    int loff = ((lane >> 4) << 4) + (((lane >> 2) & 3) << 6) + (lane & 3);
#pragma unroll
    for (int i = 0; i < 4; ++i)
#pragma unroll
        for (int j = 0; j < 4; ++j) {
            int base = mbase + rbase + loff + i * 256 + j * 4096;
            op[base]      = acc[i][j][0];
            op[base + 4]  = acc[i][j][1];   // D row digit -> axis10 (stride 4)
            op[base + 8]  = acc[i][j][2];
            op[base + 12] = acc[i][j][3];
        }
}

// ============================================================================
extern "C" void kernel_launch(void* const* d_in, const int* in_sizes, int n_in,
                              void* d_out, int out_size, void* d_ws,
                              size_t ws_size, hipStream_t stream) {
    const float* qre = (const float*)d_in[0];
    const float* qim = (const float*)d_in[1];
    const float* gre = (const float*)d_in[2];
    const float* gim = (const float*)d_in[3];
    float* out = (float*)d_out;

    const size_t BT_BYTES = 2048ull * 2048 * 2 * 2;   // 16 MB
    u16* Bh = (u16*)d_ws;
    u16* Bl = Bh + 2048ull * 2048;

    bool haveB = ws_size >= BT_BYTES;

    if (haveB) {
        pack_gate<<<2048, 256, 0, stream>>>(gre, gim, Bh, Bl);
        gemm_k<true><<<2048, 256, 0, stream>>>(qre, qim, gre, gim, Bh, Bl,
                                               out);
    } else {
        gemm_k<false><<<2048, 256, 0, stream>>>(qre, qim, gre, gim, Bh, Bl,
                                                out);
    }
}

// Round 4
// 564.793 us; speedup vs baseline: 1.0943x; 1.0943x over previous
//
#include <hip/hip_runtime.h>

// ============================================================================
// Qudit gate apply: state (4,)^12 complex (f32 re/im planes), gate 1024x1024
// complex on target axes (0,3,5,8,11).
// GEMM: C[b][n] = sum_k A[b][k] * Bt[n][k]
//   A[b][k]  : k<1024 -> qs_re gathered at (b, c=k); k>=1024 -> qs_im
//   Bt[n][k] : complex-as-real blocks [[Gr, -Gi],[Gi, Gr]] (transposed layout)
//   C[b][n]  : n<1024 -> out_re at (b, r=n); else out_im
// Precision: split-bf16 (x = hi + lo), 3 MFMA terms hh+hl+lh -> ~2^-17 rel err.
// R3: fused A-gather (no pack_state).  R4 changes (conflict diagnosis):
//  - cvtwrite now writes uint4 (q-pairs): same byte layout, but per-inst bank
//    distribution is exactly balanced (8 words/bank = min) -> 16.8M LDS bank
//    conflicts -> ~0.
//  - bsplit via native RNE casts (compiler emits v_cvt_pk_bf16_f32) instead
//    of bit arithmetic: ~1/3 the VALU.
// ============================================================================

typedef unsigned short u16;
typedef unsigned int u32;
typedef __bf16 bf16x8 __attribute__((ext_vector_type(8)));
typedef __bf16 bf16x2 __attribute__((ext_vector_type(2)));
typedef float f32x4 __attribute__((ext_vector_type(4)));

// ---- digit scatter helpers -------------------------------------------------
// batch digits (LSB first) -> axes 10,9,7,6,4,2,1 with float strides
// 4,16,256,1024,16384,262144,1048576
__device__ __forceinline__ int scat_b(int b) {
    return ((b & 3) << 2) + (((b >> 2) & 3) << 4) + (((b >> 4) & 3) << 8) +
           (((b >> 6) & 3) << 10) + (((b >> 8) & 3) << 14) +
           (((b >> 10) & 3) << 18) + (((b >> 12) & 3) << 20);
}

// pack two f32 -> u32 of 2 bf16 (RNE), and residuals likewise
__device__ __forceinline__ void bsplit2(float x, float y, u32& hw, u32& lw) {
    __bf16 hx = (__bf16)x, hy = (__bf16)y;
    float rx = x - (float)hx, ry = y - (float)hy;
    bf16x2 hp, lp;
    hp.x = hx; hp.y = hy;
    lp.x = (__bf16)rx; lp.y = (__bf16)ry;
    hw = __builtin_bit_cast(u32, hp);
    lw = __builtin_bit_cast(u32, lp);
}

// legacy scalar split for pack_gate (bit-exact same rounding)
__device__ __forceinline__ void bsplit(float x, u16& h, u16& l) {
    __bf16 hx = (__bf16)x;
    float r = x - (float)hx;
    __bf16 lx = (__bf16)r;
    h = __builtin_bit_cast(u16, hx);
    l = __builtin_bit_cast(u16, lx);
}

__device__ __forceinline__ f32x4 mfma16(bf16x8 a, bf16x8 b, f32x4 c) {
    return __builtin_amdgcn_mfma_f32_16x16x32_bf16(a, b, c, 0, 0, 0);
}

__device__ __forceinline__ void gll16(const void* g, void* l) {
    __builtin_amdgcn_global_load_lds(
        (const __attribute__((address_space(1))) u32*)g,
        (__attribute__((address_space(3))) u32*)l, 16, 0, 0);
}

// ============================================================================
// pack_gate: Bt[n][k] bf16 hi/lo, n-major rows of 2048.  grid 2048 x 256
// ============================================================================
__global__ void pack_gate(const float* __restrict__ gre,
                          const float* __restrict__ gim,
                          u16* __restrict__ bh, u16* __restrict__ bl) {
    int t = blockIdx.x * 256 + threadIdx.x;  // 524288 threads
    int n = t >> 8;                          // 0..2047
    int k = (t & 255) << 3;                  // 8-elem segment
    bool nim = n >= 1024, kim = k >= 1024;
    const float* src = kim ? (nim ? gre : gim) : (nim ? gim : gre);
    float sgn = (kim && !nim) ? -1.f : 1.f;
    int r = n & 1023, c = k & 1023;
    const float* p = src + r * 1024 + c;
    float4 v0 = *(const float4*)p;
    float4 v1 = *(const float4*)(p + 4);
    uint4 hw, lw;
    bsplit2(v0.x * sgn, v0.y * sgn, hw.x, lw.x);
    bsplit2(v0.z * sgn, v0.w * sgn, hw.y, lw.y);
    bsplit2(v1.x * sgn, v1.y * sgn, hw.z, lw.z);
    bsplit2(v1.z * sgn, v1.w * sgn, hw.w, lw.w);
    size_t o = (size_t)n * 2048 + k;
    *(uint4*)(bh + o) = hw;
    *(uint4*)(bl + o) = lw;
}

// ============================================================================
// GEMM:  BM=BN=128, BK=64, 256 thr (4 waves 2x2, wave tile 64x64 = 4x4 frags
// of 16x16x32).  LDS tiles XOR-swizzled: byte ^= (row&7)<<4.
// A: gathered f32 from state, bsplit2, swizzled uint4 ds_write (conflict-min).
// BPACK: B staged via global_load_lds from packed ws; else gathered f32.
// ============================================================================
__device__ __forceinline__ void stage_packed(const u16* gh, const u16* gl,
                                             int row0, int kt, u16* sh,
                                             u16* sl, int wid, int lane) {
#pragma unroll
    for (int i = 0; i < 4; ++i) {
        int chunk = (wid << 2) + i;         // 16 chunks of 8 rows
        int rl = (chunk << 3) + (lane >> 3);
        size_t off = (size_t)(row0 + rl) * 2048 + kt +
                     (((lane & 7) ^ (rl & 7)) << 3);  // pre-swizzled source
        gll16(gh + off, sh + chunk * 512);  // dest wave-uniform, linear
        gll16(gl + off, sl + chunk * 512);
    }
}

// 16B writes, q-pairs; byte layout identical to 8B version (key has no bit 3)
__device__ __forceinline__ void cvtwrite(const float4 v[8], int row, int half,
                                         char* sh, char* sl) {
    int swz = (row & 7) << 4;
    int rbase = row * 128;
#pragma unroll
    for (int qq = 0; qq < 4; ++qq) {
        const float4 a = v[2 * qq];
        const float4 b = v[2 * qq + 1];
        uint4 hw, lw;
        bsplit2(a.x, a.y, hw.x, lw.x);
        bsplit2(a.z, a.w, hw.y, lw.y);
        bsplit2(b.x, b.y, hw.z, lw.z);
        bsplit2(b.z, b.w, hw.w, lw.w);
        int off = rbase + (((half << 6) + (qq << 4)) ^ swz);
        *(uint4*)(sh + off) = hw;
        *(uint4*)(sl + off) = lw;
    }
}

// A gather: 8 c-quads for (row, half) of tile at kt
// v[q] = state floats at c4=0..3, c3=q&3, c2=2*half+(q>>2), c1/c0 from kt
__device__ __forceinline__ void loadA(const float* qre, const float* qim,
                                      int bb, int half, int kt, float4 v[8]) {
    const float* src = (kt < 1024) ? qre : qim;
    int km = kt & 1023;
    int cof = (((km >> 6) & 3) << 16) + (((km >> 8) & 3) << 22);
    const float* p = src + bb + cof + (half << 13);
    v[0] = *(const float4*)(p);
    v[1] = *(const float4*)(p + 64);
    v[2] = *(const float4*)(p + 128);
    v[3] = *(const float4*)(p + 192);
    v[4] = *(const float4*)(p + 4096);
    v[5] = *(const float4*)(p + 4160);
    v[6] = *(const float4*)(p + 4224);
    v[7] = *(const float4*)(p + 4288);
}

// B gather from gate f32 (no-ws fallback); sign folded via sgn
__device__ __forceinline__ void loadB(const float* gre, const float* gim,
                                      int n0, int kt, int row, int half,
                                      float4 v[8], float& sgn) {
    bool nim = n0 >= 1024, kim = kt >= 1024;
    const float* src = kim ? (nim ? gre : gim) : (nim ? gim : gre);
    sgn = (kim && !nim) ? -1.f : 1.f;
    int r = (n0 + row) & 1023;
    const float* p = src + r * 1024 + (kt & 1023) + (half << 5);
#pragma unroll
    for (int q = 0; q < 8; ++q) v[q] = *(const float4*)(p + q * 4);
}

template <bool BPACK>
__global__ __launch_bounds__(256, 2) void gemm_k(
    const float* __restrict__ qre, const float* __restrict__ qim,
    const float* __restrict__ gre, const float* __restrict__ gim,
    const u16* __restrict__ Bh, const u16* __restrict__ Bl,
    float* __restrict__ out) {
    __shared__ __align__(16) u16 sAh[128 * 64];
    __shared__ __align__(16) u16 sAl[128 * 64];
    __shared__ __align__(16) u16 sBh[128 * 64];
    __shared__ __align__(16) u16 sBl[128 * 64];

    int tid = threadIdx.x;
    int lane = tid & 63, wid = tid >> 6;

    // XCD-aware bijective swizzle (2048 % 8 == 0), nt-major decomposition:
    // XCD x owns 2 nt-panels x 128 mt -> packed B L2-resident per XCD.
    int bid = blockIdx.x;
    int orig = ((bid & 7) << 8) + (bid >> 3);
    int nt = orig >> 7, mt = orig & 127;
    int m0 = mt << 7, n0 = nt << 7;

    // staging role
    int srow = tid >> 1, shalf = tid & 1;
    int bb = scat_b(m0 + srow);

    float4 av[8], bv[8];
    float bsgn = 1.f;
    loadA(qre, qim, bb, shalf, 0, av);
    if constexpr (!BPACK) loadB(gre, gim, n0, 0, srow, shalf, bv, bsgn);
    if constexpr (BPACK) stage_packed(Bh, Bl, n0, 0, sBh, sBl, wid, lane);

    // compute role
    int wm = wid >> 1, wn = wid & 1;
    int aoffs[4], boffs[4];
#pragma unroll
    for (int f = 0; f < 4; ++f) {
        aoffs[f] = (wm * 64 + f * 16 + (lane & 15)) * 128;
        boffs[f] = (wn * 64 + f * 16 + (lane & 15)) * 128;
    }
    int swz = (lane & 7) << 4;
    int koff0 = (((lane >> 4) << 4)) ^ swz;
    int koff1 = (64 + ((lane >> 4) << 4)) ^ swz;

    f32x4 acc[4][4];
#pragma unroll
    for (int i = 0; i < 4; ++i)
#pragma unroll
        for (int j = 0; j < 4; ++j) acc[i][j] = (f32x4){0.f, 0.f, 0.f, 0.f};

    for (int it = 0; it < 32; ++it) {
        int kt = it << 6;
        cvtwrite(av, srow, shalf, (char*)sAh, (char*)sAl);
        if constexpr (!BPACK) {
            float4 bs[8];
#pragma unroll
            for (int q = 0; q < 8; ++q) {
                bs[q].x = bv[q].x * bsgn; bs[q].y = bv[q].y * bsgn;
                bs[q].z = bv[q].z * bsgn; bs[q].w = bv[q].w * bsgn;
            }
            cvtwrite(bs, srow, shalf, (char*)sBh, (char*)sBl);
        }
        __syncthreads();  // LDS writes + global_load_lds(kt) complete
        if (it < 31) {    // prefetch next gathered tiles into regs
            loadA(qre, qim, bb, shalf, kt + 64, av);
            if constexpr (!BPACK)
                loadB(gre, gim, n0, kt + 64, srow, shalf, bv, bsgn);
        }
#pragma unroll
        for (int ks = 0; ks < 2; ++ks) {
            int ko = ks ? koff1 : koff0;
            bf16x8 a_h[4], a_l[4], b_h[4], b_l[4];
#pragma unroll
            for (int f = 0; f < 4; ++f) {
                a_h[f] = *(const bf16x8*)((const char*)sAh + aoffs[f] + ko);
                a_l[f] = *(const bf16x8*)((const char*)sAl + aoffs[f] + ko);
                b_h[f] = *(const bf16x8*)((const char*)sBh + boffs[f] + ko);
                b_l[f] = *(const bf16x8*)((const char*)sBl + boffs[f] + ko);
            }
#pragma unroll
            for (int i = 0; i < 4; ++i)
#pragma unroll
                for (int j = 0; j < 4; ++j) {
                    acc[i][j] = mfma16(a_h[i], b_h[j], acc[i][j]);
                    acc[i][j] = mfma16(a_l[i], b_h[j], acc[i][j]);
                    acc[i][j] = mfma16(a_h[i], b_l[j], acc[i][j]);
                }
        }
        __syncthreads();  // frag reads done before next overwrite
        if (it < 31) {
            if constexpr (BPACK)
                stage_packed(Bh, Bl, n0, kt + 64, sBh, sBl, wid, lane);
        }
    }

    // epilogue: scatter f32 directly into state layout
    int mbase = scat_b(m0 + wm * 64);
    int nw = n0 + wn * 64;
    float* op = out + ((nw >> 10) << 24);  // re plane or im plane (+16M)
    int rb = nw & 1023;
    int rbase = (((rb >> 2) & 3) << 6) + (((rb >> 4) & 3) << 12) +
                (((rb >> 6) & 3) << 16) + (((rb >> 8) & 3) << 22);
    int loff = ((lane >> 4) << 4) + (((lane >> 2) & 3) << 6) + (lane & 3);
#pragma unroll
    for (int i = 0; i < 4; ++i)
#pragma unroll
        for (int j = 0; j < 4; ++j) {
            int base = mbase + rbase + loff + i * 256 + j * 4096;
            op[base]      = acc[i][j][0];
            op[base + 4]  = acc[i][j][1];   // D row digit -> axis10 (stride 4)
            op[base + 8]  = acc[i][j][2];
            op[base + 12] = acc[i][j][3];
        }
}

// ============================================================================
extern "C" void kernel_launch(void* const* d_in, const int* in_sizes, int n_in,
                              void* d_out, int out_size, void* d_ws,
                              size_t ws_size, hipStream_t stream) {
    const float* qre = (const float*)d_in[0];
    const float* qim = (const float*)d_in[1];
    const float* gre = (const float*)d_in[2];
    const float* gim = (const float*)d_in[3];
    float* out = (float*)d_out;

    const size_t BT_BYTES = 2048ull * 2048 * 2 * 2;   // 16 MB
    u16* Bh = (u16*)d_ws;
    u16* Bl = Bh + 2048ull * 2048;

    bool haveB = ws_size >= BT_BYTES;

    if (haveB) {
        pack_gate<<<2048, 256, 0, stream>>>(gre, gim, Bh, Bl);
        gemm_k<true><<<2048, 256, 0, stream>>>(qre, qim, gre, gim, Bh, Bl,
                                               out);
    } else {
        gemm_k<false><<<2048, 256, 0, stream>>>(qre, qim, gre, gim, Bh, Bl,
                                                out);
    }
}